// Round 14
// baseline (1430.217 us; speedup 1.0000x reference)
//
#include <hip/hip_runtime.h>
#include <cmath>

#define N_NODES 50000
#define N_EDGES 800000
#define F_IN 92
#define DIM 64
#define EF 50
#define NLAYER 3
#define NGRAPH 128
#define ZROWS 178   // 2*DIM + EF

using short8 = __attribute__((ext_vector_type(8))) short;
using f32x4  = __attribute__((ext_vector_type(4))) float;

// float -> bf16 bits (RNE)
__device__ __forceinline__ unsigned short f2bf(float v) {
    unsigned int u = __float_as_uint(v);
    return (unsigned short)((u + 0x7FFFu + ((u >> 16) & 1u)) >> 16);
}
__device__ __forceinline__ float bf2f(unsigned short h) {
    return __uint_as_float(((unsigned int)h) << 16);
}

// ---------------- pre FC: h = relu(x @ pre_W + pre_b); also write bf16 hi/lo --
__global__ __launch_bounds__(256, 3) void pre_fc(const float* __restrict__ x,
                                                 const float* __restrict__ W,
                                                 const float* __restrict__ b,
                                                 float* __restrict__ h,
                                                 unsigned short* __restrict__ hh,
                                                 unsigned short* __restrict__ hl, int N)
{
    const int lane = threadIdx.x & 63;
    const int wid  = blockIdx.x * (blockDim.x >> 6) + (threadIdx.x >> 6);
    const int nw   = gridDim.x * (blockDim.x >> 6);
    float w[F_IN];
#pragma unroll
    for (int k = 0; k < F_IN; ++k) w[k] = W[k * DIM + lane];
    const float bb = b[lane];
#pragma unroll 1
    for (int n = wid; n < N; n += nw) {
        const int nu = __builtin_amdgcn_readfirstlane(n);
        const float* xr = x + (size_t)nu * F_IN;
        float a = bb;
#pragma unroll
        for (int k = 0; k < F_IN; ++k) a = fmaf(xr[k], w[k], a);
        const float rv = fmaxf(a, 0.f);
        const size_t idx = (size_t)nu * DIM + lane;
        h[idx] = rv;
        const unsigned short hb = f2bf(rv);
        hh[idx] = hb;
        hl[idx] = f2bf(rv - bf2f(hb));
    }
}

// ---------------- degree + graph-node counts ----------------
__global__ __launch_bounds__(256) void deg_cnt(const int* __restrict__ ei, int E,
                                               const int* __restrict__ batch, int N,
                                               float* __restrict__ deg,
                                               float* __restrict__ cnt)
{
    const int i = blockIdx.x * blockDim.x + threadIdx.x;
    const int stride = gridDim.x * blockDim.x;
    for (int e = i; e < E; e += stride) unsafeAtomicAdd(&deg[ei[E + e]], 1.f);
    for (int n = i; n < N; n += stride) unsafeAtomicAdd(&cnt[batch[n]], 1.f);
}

// ---------------- prep: transpose+bf16-split edge-attr weights ----------------
__global__ __launch_bounds__(256) void prep_wsplit(const float* __restrict__ Wf,
                                                   const float* __restrict__ Ws,
                                                   unsigned short* __restrict__ Wth,
                                                   unsigned short* __restrict__ Wtl)
{
    const int i = blockIdx.x * blockDim.x + threadIdx.x;
    if (i >= NLAYER * 128 * 64) return;
    const int l = i >> 13;            // /8192
    const int rem = i & 8191;
    const int c = rem >> 6;
    const int k = rem & 63;
    float v = 0.f;
    if (k < EF) {
        const size_t base = (size_t)l * ZROWS * DIM + (size_t)(2 * DIM + k) * DIM;
        v = (c < 64) ? Wf[base + c] : Ws[base + (c - 64)];
    }
    const unsigned short hb = f2bf(v);
    Wth[i] = hb;
    Wtl[i] = f2bf(v - bf2f(hb));
}

// ---------------- prep: transpose+bf16-split node weights + packed bias -------
__global__ __launch_bounds__(256) void prep_nwsplit(const float* __restrict__ Wf,
                                                    const float* __restrict__ Ws,
                                                    const float* __restrict__ bf,
                                                    const float* __restrict__ bs,
                                                    unsigned short* __restrict__ Wnh,
                                                    unsigned short* __restrict__ Wnl,
                                                    float* __restrict__ pbias)
{
    const int i = blockIdx.x * blockDim.x + threadIdx.x;
    if (i >= NLAYER * 256 * 64) return;
    const int l = i >> 14;            // /16384
    const int rem = i & 16383;
    const int c = rem >> 6;
    const int k = rem & 63;
    const size_t lb = (size_t)l * ZROWS * DIM;
    float v;
    if (c < 64)       v = Wf[lb + (size_t)k * DIM + c];
    else if (c < 128) v = Ws[lb + (size_t)k * DIM + (c - 64)];
    else if (c < 192) v = Wf[lb + (size_t)(64 + k) * DIM + (c - 128)];
    else              v = Ws[lb + (size_t)(64 + k) * DIM + (c - 192)];
    const unsigned short hb = f2bf(v);
    Wnh[i] = hb;
    Wnl[i] = f2bf(v - bf2f(hb));
    if (k == 0)
        pbias[l * 256 + c] = (c < 64) ? bf[l * DIM + c]
                           : ((c < 128) ? bs[l * DIM + (c - 64)] : 0.f);
}

// ---------------- node projections via MFMA ----------------
#define HS_STR 72
__global__ __launch_bounds__(512, 4) void node_proj_mfma(
    const unsigned short* __restrict__ hh,
    const unsigned short* __restrict__ hl,
    const unsigned short* __restrict__ Wnh,
    const unsigned short* __restrict__ Wnl,
    const float* __restrict__ pbias,
    float* __restrict__ Pd, float* __restrict__ Ps, int N)
{
    __shared__ unsigned short lh[64 * HS_STR];
    __shared__ unsigned short ll[64 * HS_STR];
    const int tid = threadIdx.x;
    const int n0 = blockIdx.x * 64;

    {
        const int row = tid >> 3, c8 = tid & 7;
        const int n = n0 + row;
        short8 hv = (short8){0,0,0,0,0,0,0,0};
        short8 lv = (short8){0,0,0,0,0,0,0,0};
        if (n < N) {
            const size_t gs = (size_t)n * 64 + c8 * 8;
            hv = *reinterpret_cast<const short8*>(hh + gs);
            lv = *reinterpret_cast<const short8*>(hl + gs);
        }
        *reinterpret_cast<short8*>(lh + row * HS_STR + c8 * 8) = hv;
        *reinterpret_cast<short8*>(ll + row * HS_STR + c8 * 8) = lv;
    }
    __syncthreads();

    const int l  = tid & 63;
    const int wv = __builtin_amdgcn_readfirstlane(tid >> 6);
    const int mt = wv & 3, ng = wv >> 2;
    const int r = l & 15, g = l >> 4;
    const int arow = mt * 16 + r;

    short8 ah[2], al[2];
#pragma unroll
    for (int kc = 0; kc < 2; ++kc) {
        const int off = arow * HS_STR + kc * 32 + g * 8;
        ah[kc] = *reinterpret_cast<const short8*>(lh + off);
        al[kc] = *reinterpret_cast<const short8*>(ll + off);
    }

    f32x4 acc[8];
#pragma unroll
    for (int nt = 0; nt < 8; ++nt) acc[nt] = (f32x4){0.f, 0.f, 0.f, 0.f};

#pragma unroll
    for (int nt = 0; nt < 8; ++nt) {
        const int col = ng * 128 + nt * 16 + r;
        const unsigned short* bp = Wnh + (size_t)col * 64 + g * 8;
        const unsigned short* lp = Wnl + (size_t)col * 64 + g * 8;
#pragma unroll
        for (int kc = 0; kc < 2; ++kc) {
            const short8 bh = *reinterpret_cast<const short8*>(bp + kc * 32);
            const short8 bl = *reinterpret_cast<const short8*>(lp + kc * 32);
            acc[nt] = __builtin_amdgcn_mfma_f32_16x16x32_bf16(ah[kc], bh, acc[nt], 0, 0, 0);
            acc[nt] = __builtin_amdgcn_mfma_f32_16x16x32_bf16(ah[kc], bl, acc[nt], 0, 0, 0);
            acc[nt] = __builtin_amdgcn_mfma_f32_16x16x32_bf16(al[kc], bh, acc[nt], 0, 0, 0);
        }
    }

    float* P = ng ? Ps : Pd;
#pragma unroll
    for (int nt = 0; nt < 8; ++nt) {
        const int c = nt * 16 + r;
        const float bias = ng ? 0.f : pbias[c];
#pragma unroll
        for (int rr = 0; rr < 4; ++rr) {
            const int n = n0 + mt * 16 + g * 4 + rr;
            if (n < N) P[(size_t)n * 128 + c] = acc[nt][rr] + bias;
        }
    }
}

// ---------------- fused edge kernel (unsorted, register epilogue, MLP) -------
// One block = 512 threads (8 waves) = 128 consecutive edges; wave wv owns the
// 16-edge tile [wv*16, wv*16+16).
// (512,4): 256-VGPR budget so all 64 epilogue gather results stay live.
// Order: A-frags -> issue ei + all 64 Pd/Ps gathers -> 48 MFMAs (hide gather
// latency) -> gate in registers -> atomics. No out_lds, one sync.
#define EA_STR 72
__global__ __launch_bounds__(512, 4) void edge_fused(const int* __restrict__ ei,
                                                     const float* __restrict__ eattr,
                                                     const float* __restrict__ Pd,
                                                     const float* __restrict__ Ps,
                                                     const unsigned short* __restrict__ Wth,
                                                     const unsigned short* __restrict__ Wtl,
                                                     float* __restrict__ agg, int E)
{
    __shared__ unsigned short lds_h[128 * EA_STR];
    __shared__ unsigned short lds_l[128 * EA_STR];

    const int tid = threadIdx.x;
    const int e0  = blockIdx.x * 128;

    // ---- stage 128 contiguous eattr rows, convert f32 -> bf16 hi/lo ----
#pragma unroll
    for (int it = 0; it < 2; ++it) {
        const int u = tid + it * 512;          // 0..1023
        const int row = u >> 3;
        const int c8  = u & 7;
        const float* er = eattr + (size_t)(e0 + row) * EF;
        short8 hv, lv;
#pragma unroll
        for (int j = 0; j < 8; ++j) {
            const int k = c8 * 8 + j;
            const float v = (k < EF) ? er[k] : 0.f;
            const unsigned short hb = f2bf(v);
            hv[j] = (short)hb;
            lv[j] = (short)f2bf(v - bf2f(hb));
        }
        *reinterpret_cast<short8*>(lds_h + row * EA_STR + c8 * 8) = hv;
        *reinterpret_cast<short8*>(lds_l + row * EA_STR + c8 * 8) = lv;
    }
    __syncthreads();

    const int l  = tid & 63;
    const int wv = __builtin_amdgcn_readfirstlane(tid >> 6);   // 0..7
    const int r  = l & 15;
    const int g  = l >> 4;
    const int rbase = wv * 16;      // wave's edge-tile base (local)

    // ---- A fragments (16 edges x 64 k) ----
    short8 ah[2], al[2];
#pragma unroll
    for (int kc = 0; kc < 2; ++kc) {
        const int off = (rbase + r) * EA_STR + kc * 32 + g * 8;
        ah[kc] = *reinterpret_cast<const short8*>(lds_h + off);
        al[kc] = *reinterpret_cast<const short8*>(lds_l + off);
    }

    // ---- issue epilogue gathers EARLY (independent of MFMA chain) ----
    int dds[4], sss[4];
#pragma unroll
    for (int rr = 0; rr < 4; ++rr) {
        const int eg = e0 + rbase + g * 4 + rr;    // global edge id
        dds[rr] = ei[E + eg];                      // dst
        sss[rr] = ei[eg];                          // src
    }
    float pdv[4][8], psv[4][8];
#pragma unroll
    for (int rr = 0; rr < 4; ++rr) {
        const float* pdr = Pd + (size_t)dds[rr] * 128 + r;
        const float* psr = Ps + (size_t)sss[rr] * 128 + r;
#pragma unroll
        for (int nt = 0; nt < 8; ++nt) {
            pdv[rr][nt] = pdr[nt * 16];
            psv[rr][nt] = psr[nt * 16];
        }
    }

    // ---- 48 MFMAs: all 128 cols (gather latency hides under these) ----
    f32x4 acc[8];
#pragma unroll
    for (int nt = 0; nt < 8; ++nt) acc[nt] = (f32x4){0.f, 0.f, 0.f, 0.f};
#pragma unroll
    for (int nt = 0; nt < 8; ++nt) {
        const int col = nt * 16 + r;
        const unsigned short* bp = Wth + (size_t)col * 64 + g * 8;
        const unsigned short* lp = Wtl + (size_t)col * 64 + g * 8;
#pragma unroll
        for (int kc = 0; kc < 2; ++kc) {
            const short8 bh = *reinterpret_cast<const short8*>(bp + kc * 32);
            const short8 bl = *reinterpret_cast<const short8*>(lp + kc * 32);
            acc[nt] = __builtin_amdgcn_mfma_f32_16x16x32_bf16(ah[kc], bh, acc[nt], 0, 0, 0);
            acc[nt] = __builtin_amdgcn_mfma_f32_16x16x32_bf16(ah[kc], bl, acc[nt], 0, 0, 0);
            acc[nt] = __builtin_amdgcn_mfma_f32_16x16x32_bf16(al[kc], bh, acc[nt], 0, 0, 0);
        }
    }

    // ---- register epilogue: C row (lane>>4)*4+rr, col nt*16+r ----
#pragma unroll
    for (int rr = 0; rr < 4; ++rr) {
        float* ag = agg + (size_t)dds[rr] * DIM + r;
#pragma unroll
        for (int nt = 0; nt < 4; ++nt) {
            const float zf = acc[nt][rr]     + pdv[rr][nt]     + psv[rr][nt];
            const float zs = acc[nt + 4][rr] + pdv[rr][nt + 4] + psv[rr][nt + 4];
            const float sig = 1.f / (1.f + __expf(-zf));
            const float sp  = fmaxf(zs, 0.f) + __logf(1.f + __expf(-fabsf(zs)));
            unsafeAtomicAdd(ag + nt * 16, sig * sp);
        }
    }
}

// ---------------- node update: h = BN(h + agg/deg); also write bf16 hi/lo ----
__global__ __launch_bounds__(256) void node_update(float* __restrict__ h,
                                                   unsigned short* __restrict__ hh,
                                                   unsigned short* __restrict__ hl,
                                                   const float* __restrict__ agg,
                                                   const float* __restrict__ deg,
                                                   const float* __restrict__ gamma,
                                                   const float* __restrict__ beta,
                                                   const float* __restrict__ mean,
                                                   const float* __restrict__ var, int N)
{
    const int lane = threadIdx.x & 63;
    const float g  = gamma[lane];
    const float bt = beta[lane];
    const float mn = mean[lane];
    const float iv = rsqrtf(var[lane] + 1e-5f);
    const int idx = blockIdx.x * blockDim.x + threadIdx.x;
    const int stride = gridDim.x * blockDim.x;  // multiple of 64
    const int total = N * DIM;
    for (int i = idx; i < total; i += stride) {
        const int n = i >> 6;
        const float inv = 1.f / fmaxf(deg[n], 1.f);
        const float v = h[i] + agg[i] * inv;
        const float rv = fmaf(g, (v - mn) * iv, bt);
        h[i] = rv;
        const unsigned short hb = f2bf(rv);
        hh[i] = hb;
        hl[i] = f2bf(rv - bf2f(hb));
    }
}

// ---------------- global mean pool (sum part) ----------------
__global__ __launch_bounds__(256) void pool_sum(const float* __restrict__ h,
                                                const int* __restrict__ batch,
                                                float* __restrict__ gsum, int N)
{
    const int lane = threadIdx.x & 63;
    const int wid  = blockIdx.x * (blockDim.x >> 6) + (threadIdx.x >> 6);
    const int nw   = gridDim.x * (blockDim.x >> 6);
    for (int n = wid; n < N; n += nw) {
        const int nu = __builtin_amdgcn_readfirstlane(n);
        const int b = batch[nu];
        unsafeAtomicAdd(&gsum[(size_t)b * DIM + lane], h[(size_t)nu * DIM + lane]);
    }
}

// ---------------- head: g=relu(mean@postW+postb); out = g@outW+outb ----------------
__global__ __launch_bounds__(64) void head(const float* __restrict__ gsum,
                                           const float* __restrict__ cnt,
                                           const float* __restrict__ postW,
                                           const float* __restrict__ postb,
                                           const float* __restrict__ outW,
                                           const float* __restrict__ outb,
                                           float* __restrict__ out)
{
    const int gi = blockIdx.x;
    const int lane = threadIdx.x;
    const float inv = 1.f / fmaxf(cnt[gi], 1.f);
    const float gval = gsum[(size_t)gi * DIM + lane] * inv;
    float acc = postb[lane];
#pragma unroll
    for (int k = 0; k < DIM; ++k) acc = fmaf(__shfl(gval, k, 64), postW[k * DIM + lane], acc);
    const float t = fmaxf(acc, 0.f);
    float prod = t * outW[lane];
#pragma unroll
    for (int off = 32; off > 0; off >>= 1) prod += __shfl_down(prod, off, 64);
    if (lane == 0) out[gi] = prod + outb[0];
}

extern "C" void kernel_launch(void* const* d_in, const int* in_sizes, int n_in,
                              void* d_out, int out_size, void* d_ws, size_t ws_size,
                              hipStream_t stream)
{
    const float* x     = (const float*)d_in[0];
    const int*   ei    = (const int*)d_in[1];
    const float* eattr = (const float*)d_in[2];
    const int*   batch = (const int*)d_in[3];
    const float* preW  = (const float*)d_in[4];
    const float* preb  = (const float*)d_in[5];
    const float* Wf    = (const float*)d_in[6];
    const float* bf    = (const float*)d_in[7];
    const float* Ws    = (const float*)d_in[8];
    const float* bs    = (const float*)d_in[9];
    const float* gamma = (const float*)d_in[10];
    const float* beta  = (const float*)d_in[11];
    const float* mean  = (const float*)d_in[12];
    const float* var   = (const float*)d_in[13];
    const float* postW = (const float*)d_in[14];
    const float* postb = (const float*)d_in[15];
    const float* outW  = (const float*)d_in[16];
    const float* outb  = (const float*)d_in[17];
    float* out = (float*)d_out;

    const int N = N_NODES, E = N_EDGES, G = NGRAPH;

    char* p = (char*)d_ws;
    unsigned short* hh = (unsigned short*)p; p += (size_t)N * DIM * 2;
    unsigned short* hl = (unsigned short*)p; p += (size_t)N * DIM * 2;
    float* h      = (float*)p; p += (size_t)N * DIM * 4;
    float* Pd     = (float*)p; p += (size_t)N * 128 * 4;
    float* Ps     = (float*)p; p += (size_t)N * 128 * 4;
    float* agg    = (float*)p; p += (size_t)N * DIM * 4;
    // zeroed-together block: gsum | cnt | deg
    float* gsum   = (float*)p; p += (size_t)G * DIM * 4;
    float* cnt    = (float*)p; p += (size_t)G * 4;
    float* deg    = (float*)p; p += (size_t)N * 4;
    unsigned short* Wth = (unsigned short*)p; p += (size_t)NLAYER * 128 * 64 * 2;
    unsigned short* Wtl = (unsigned short*)p; p += (size_t)NLAYER * 128 * 64 * 2;
    unsigned short* Wnh = (unsigned short*)p; p += (size_t)NLAYER * 256 * 64 * 2;
    unsigned short* Wnl = (unsigned short*)p; p += (size_t)NLAYER * 256 * 64 * 2;
    float* pbias  = (float*)p; p += (size_t)NLAYER * 256 * 4;

    hipMemsetAsync(gsum, 0, ((size_t)G * DIM + G + N) * 4, stream);

    deg_cnt<<<512, 256, 0, stream>>>(ei, E, batch, N, deg, cnt);
    prep_wsplit<<<(NLAYER * 128 * 64 + 255) / 256, 256, 0, stream>>>(Wf, Ws, Wth, Wtl);
    prep_nwsplit<<<(NLAYER * 256 * 64 + 255) / 256, 256, 0, stream>>>(Wf, Ws, bf, bs,
                                                                      Wnh, Wnl, pbias);

    pre_fc<<<512, 256, 0, stream>>>(x, preW, preb, h, hh, hl, N);

    const int nblk = (N + 63) / 64;
    for (int l = 0; l < NLAYER; ++l) {
        hipMemsetAsync(agg, 0, (size_t)N * DIM * 4, stream);
        node_proj_mfma<<<nblk, 512, 0, stream>>>(hh, hl,
                                                 Wnh + (size_t)l * 16384,
                                                 Wnl + (size_t)l * 16384,
                                                 pbias + (size_t)l * 256, Pd, Ps, N);
        edge_fused<<<E / 128, 512, 0, stream>>>(ei, eattr, Pd, Ps,
                                                Wth + (size_t)l * 8192,
                                                Wtl + (size_t)l * 8192, agg, E);
        node_update<<<1024, 256, 0, stream>>>(h, hh, hl, agg, deg, gamma + l * DIM,
                                              beta + l * DIM, mean + l * DIM,
                                              var + l * DIM, N);
    }

    pool_sum<<<512, 256, 0, stream>>>(h, batch, gsum, N);
    head<<<G, 64, 0, stream>>>(gsum, cnt, postW, postb, outW, outb, out);
}

// Round 15
// 1095.297 us; speedup vs baseline: 1.3058x; 1.3058x over previous
//
#include <hip/hip_runtime.h>
#include <cmath>

#define N_NODES 50000
#define N_EDGES 800000
#define F_IN 92
#define DIM 64
#define EF 50
#define NLAYER 3
#define NGRAPH 128
#define ZROWS 178   // 2*DIM + EF

using short8 = __attribute__((ext_vector_type(8))) short;
using f32x4  = __attribute__((ext_vector_type(4))) float;

// float -> bf16 bits (RNE)
__device__ __forceinline__ unsigned short f2bf(float v) {
    unsigned int u = __float_as_uint(v);
    return (unsigned short)((u + 0x7FFFu + ((u >> 16) & 1u)) >> 16);
}
__device__ __forceinline__ float bf2f(unsigned short h) {
    return __uint_as_float(((unsigned int)h) << 16);
}

// ---------------- pre FC: h = relu(x @ pre_W + pre_b) ----------------
__global__ __launch_bounds__(256, 3) void pre_fc(const float* __restrict__ x,
                                                 const float* __restrict__ W,
                                                 const float* __restrict__ b,
                                                 float* __restrict__ h, int N)
{
    const int lane = threadIdx.x & 63;
    const int wid  = blockIdx.x * (blockDim.x >> 6) + (threadIdx.x >> 6);
    const int nw   = gridDim.x * (blockDim.x >> 6);
    float w[F_IN];
#pragma unroll
    for (int k = 0; k < F_IN; ++k) w[k] = W[k * DIM + lane];
    const float bb = b[lane];
#pragma unroll 1
    for (int n = wid; n < N; n += nw) {
        const int nu = __builtin_amdgcn_readfirstlane(n);
        const float* xr = x + (size_t)nu * F_IN;
        float a = bb;
#pragma unroll
        for (int k = 0; k < F_IN; ++k) a = fmaf(xr[k], w[k], a);
        h[(size_t)nu * DIM + lane] = fmaxf(a, 0.f);
    }
}

// ---------------- degree + graph-node counts ----------------
__global__ __launch_bounds__(256) void deg_cnt(const int* __restrict__ ei, int E,
                                               const int* __restrict__ batch, int N,
                                               float* __restrict__ deg,
                                               float* __restrict__ cnt)
{
    const int i = blockIdx.x * blockDim.x + threadIdx.x;
    const int stride = gridDim.x * blockDim.x;
    for (int e = i; e < E; e += stride) unsafeAtomicAdd(&deg[ei[E + e]], 1.f);
    for (int n = i; n < N; n += stride) unsafeAtomicAdd(&cnt[batch[n]], 1.f);
}

// ---------------- prep: transpose+bf16-split node weights + packed bias -------
// Wn[layer][c][k], c in [0,256): c<64 WfA col c (+bf), c<128 WsA (+bs),
// c<192 WfB, c<256 WsB.  A = weight rows 0:64 (dst/i), B = rows 64:128 (src/j).
__global__ __launch_bounds__(256) void prep_nwsplit(const float* __restrict__ Wf,
                                                    const float* __restrict__ Ws,
                                                    const float* __restrict__ bf,
                                                    const float* __restrict__ bs,
                                                    unsigned short* __restrict__ Wnh,
                                                    unsigned short* __restrict__ Wnl,
                                                    float* __restrict__ pbias)
{
    const int i = blockIdx.x * blockDim.x + threadIdx.x;
    if (i >= NLAYER * 256 * 64) return;
    const int l = i >> 14;            // /16384
    const int rem = i & 16383;
    const int c = rem >> 6;
    const int k = rem & 63;
    const size_t lb = (size_t)l * ZROWS * DIM;
    float v;
    if (c < 64)       v = Wf[lb + (size_t)k * DIM + c];
    else if (c < 128) v = Ws[lb + (size_t)k * DIM + (c - 64)];
    else if (c < 192) v = Wf[lb + (size_t)(64 + k) * DIM + (c - 128)];
    else              v = Ws[lb + (size_t)(64 + k) * DIM + (c - 192)];
    const unsigned short hb = f2bf(v);
    Wnh[i] = hb;
    Wnl[i] = f2bf(v - bf2f(hb));
    if (k == 0)
        pbias[l * 256 + c] = (c < 64) ? bf[l * DIM + c]
                           : ((c < 128) ? bs[l * DIM + (c - 64)] : 0.f);
}

// ---------------- node projections via MFMA (stage h f32 -> bf16 hi/lo) ------
#define HS_STR 72
__global__ __launch_bounds__(512) void node_proj_mfma(
    const float* __restrict__ h,
    const unsigned short* __restrict__ Wnh,
    const unsigned short* __restrict__ Wnl,
    const float* __restrict__ pbias,
    float* __restrict__ Pd, float* __restrict__ Ps, int N)
{
    __shared__ unsigned short lh[64 * HS_STR];
    __shared__ unsigned short ll[64 * HS_STR];
    const int tid = threadIdx.x;
    const int n0 = blockIdx.x * 64;

    // stage 64 h rows (f32 coalesced), convert to bf16 hi/lo in LDS
    {
        const int row = tid >> 3, c8 = tid & 7;
        const int n = n0 + row;
        short8 hv = (short8){0,0,0,0,0,0,0,0};
        short8 lv = (short8){0,0,0,0,0,0,0,0};
        if (n < N) {
            const float* hr = h + (size_t)n * DIM + c8 * 8;
#pragma unroll
            for (int j = 0; j < 8; ++j) {
                const float v = hr[j];
                const unsigned short hb = f2bf(v);
                hv[j] = (short)hb;
                lv[j] = (short)f2bf(v - bf2f(hb));
            }
        }
        *reinterpret_cast<short8*>(lh + row * HS_STR + c8 * 8) = hv;
        *reinterpret_cast<short8*>(ll + row * HS_STR + c8 * 8) = lv;
    }
    __syncthreads();

    const int l  = tid & 63;
    const int wv = __builtin_amdgcn_readfirstlane(tid >> 6);
    const int mt = wv & 3, ng = wv >> 2;
    const int r = l & 15, g = l >> 4;
    const int arow = mt * 16 + r;

    short8 ah[2], al[2];
#pragma unroll
    for (int kc = 0; kc < 2; ++kc) {
        const int off = arow * HS_STR + kc * 32 + g * 8;
        ah[kc] = *reinterpret_cast<const short8*>(lh + off);
        al[kc] = *reinterpret_cast<const short8*>(ll + off);
    }

    f32x4 acc[8];
#pragma unroll
    for (int nt = 0; nt < 8; ++nt) acc[nt] = (f32x4){0.f, 0.f, 0.f, 0.f};

#pragma unroll
    for (int nt = 0; nt < 8; ++nt) {
        const int col = ng * 128 + nt * 16 + r;
        const unsigned short* bp = Wnh + (size_t)col * 64 + g * 8;
        const unsigned short* lp = Wnl + (size_t)col * 64 + g * 8;
#pragma unroll
        for (int kc = 0; kc < 2; ++kc) {
            const short8 bh = *reinterpret_cast<const short8*>(bp + kc * 32);
            const short8 bl = *reinterpret_cast<const short8*>(lp + kc * 32);
            acc[nt] = __builtin_amdgcn_mfma_f32_16x16x32_bf16(ah[kc], bh, acc[nt], 0, 0, 0);
            acc[nt] = __builtin_amdgcn_mfma_f32_16x16x32_bf16(ah[kc], bl, acc[nt], 0, 0, 0);
            acc[nt] = __builtin_amdgcn_mfma_f32_16x16x32_bf16(al[kc], bh, acc[nt], 0, 0, 0);
        }
    }

    // C/D layout: col = lane&15, row = (lane>>4)*4 + rr
    float* P = ng ? Ps : Pd;
#pragma unroll
    for (int nt = 0; nt < 8; ++nt) {
        const int c = nt * 16 + r;
        const float bias = ng ? 0.f : pbias[c];
#pragma unroll
        for (int rr = 0; rr < 4; ++rr) {
            const int n = n0 + mt * 16 + g * 4 + rr;
            if (n < N) P[(size_t)n * 128 + c] = acc[nt][rr] + bias;
        }
    }
}

// ---------------- fused edge kernel (r7 structure, batched phase B) ----------
// One block = 512 threads (8 waves) = one tile of 64 edges.
// Phase A: wave wv computes 16 cols of the 128-dim eattr projection for all
//   64 edges; weight operand wave-uniform -> s_load (zero VGPR pressure).
// Phase B: wave wv handles 8 edges, lane = dim; ALL 32 row-gathers issued
//   branchlessly before any gate math (one latency round-trip, not 8).
#define EA_PAD 51   // odd stride -> conflict-free by-row and by-col access
#define TP_PAD 129  // odd stride -> conflict-free write (lane=e) and read (lane=dim)
__global__ __launch_bounds__(512) void edge_fused(const int* __restrict__ ei,
                                                  const float* __restrict__ eattr,
                                                  const float* __restrict__ Pd,
                                                  const float* __restrict__ Ps,
                                                  const float* __restrict__ WfE,
                                                  const float* __restrict__ WsE,
                                                  float* __restrict__ agg, int E)
{
    __shared__ float ea_lds[64 * EA_PAD];
    __shared__ float out_lds[64 * TP_PAD];

    const int tid = threadIdx.x;
    const int e0  = blockIdx.x * 64;

    // ---- stage 64 eattr rows (coalesced global read) ----
    {
        const float* src = eattr + (size_t)e0 * EF;
        for (int idx = tid; idx < 64 * EF; idx += 512) {
            const int e = idx / EF;
            const int k = idx - e * EF;
            ea_lds[e * EA_PAD + k] = src[idx];
        }
    }
    __syncthreads();

    // ---- phase A: projection, lane = edge, 16 cols per wave ----
    {
        const int e  = tid & 63;
        const int wv = __builtin_amdgcn_readfirstlane(tid >> 6);  // 0..7, uniform
        const float* Wbase = (wv < 4) ? WfE : WsE;   // uniform pointer
        const int c0 = (wv & 3) * 16;                // uniform col offset in [0,64)
        const int cb = ((wv < 4) ? 0 : 64) + c0;     // output col base in [0,128)

        float acc[16];
#pragma unroll
        for (int j = 0; j < 16; ++j) acc[j] = 0.f;

        const float* ear = ea_lds + e * EA_PAD;
#pragma unroll 5
        for (int k = 0; k < EF; ++k) {
            const float eak = ear[k];                 // ds_read, conflict-free
            const float* wr = Wbase + k * DIM + c0;   // uniform -> s_load
#pragma unroll
            for (int j = 0; j < 16; ++j) acc[j] = fmaf(eak, wr[j], acc[j]);
        }
        float* orow = out_lds + e * TP_PAD + cb;
#pragma unroll
        for (int j = 0; j < 16; ++j) orow[j] = acc[j];
    }
    __syncthreads();

    // ---- phase B: batched gathers, then gate + scatter, lane = dim ----
    {
        const int lane = tid & 63;
        const int wv   = __builtin_amdgcn_readfirstlane(tid >> 6);
        const int base = e0 + wv * 8;

        int dd[8], ss[8];
#pragma unroll
        for (int i = 0; i < 8; ++i) {
            dd[i] = ei[E + base + i];     // uniform -> s_load
            ss[i] = ei[base + i];
        }
        float pd0[8], pd1[8], ps0[8], ps1[8];
#pragma unroll
        for (int i = 0; i < 8; ++i) {     // 32 independent gathers in flight
            const float* pdr = Pd + (size_t)dd[i] * 128;
            const float* psr = Ps + (size_t)ss[i] * 128;
            pd0[i] = pdr[lane]; pd1[i] = pdr[64 + lane];
            ps0[i] = psr[lane]; ps1[i] = psr[64 + lane];
        }
#pragma unroll
        for (int i = 0; i < 8; ++i) {
            const int el = wv * 8 + i;
            const float zf = out_lds[el * TP_PAD + lane]      + pd0[i] + ps0[i];
            const float zs = out_lds[el * TP_PAD + 64 + lane] + pd1[i] + ps1[i];
            const float sig = 1.f / (1.f + __expf(-zf));
            const float sp  = fmaxf(zs, 0.f) + __logf(1.f + __expf(-fabsf(zs)));
            unsafeAtomicAdd(&agg[(size_t)dd[i] * DIM + lane], sig * sp);
        }
    }
}

// ---------------- node update: h = BN(h + agg/deg) ----------------
__global__ __launch_bounds__(256) void node_update(float* __restrict__ h,
                                                   const float* __restrict__ agg,
                                                   const float* __restrict__ deg,
                                                   const float* __restrict__ gamma,
                                                   const float* __restrict__ beta,
                                                   const float* __restrict__ mean,
                                                   const float* __restrict__ var, int N)
{
    const int lane = threadIdx.x & 63;
    const float g  = gamma[lane];
    const float bt = beta[lane];
    const float mn = mean[lane];
    const float iv = rsqrtf(var[lane] + 1e-5f);
    const int idx = blockIdx.x * blockDim.x + threadIdx.x;
    const int stride = gridDim.x * blockDim.x;  // multiple of 64
    const int total = N * DIM;
    for (int i = idx; i < total; i += stride) {
        const int n = i >> 6;
        const float inv = 1.f / fmaxf(deg[n], 1.f);
        const float v = h[i] + agg[i] * inv;
        h[i] = fmaf(g, (v - mn) * iv, bt);
    }
}

// ---------------- global mean pool (sum part) ----------------
__global__ __launch_bounds__(256) void pool_sum(const float* __restrict__ h,
                                                const int* __restrict__ batch,
                                                float* __restrict__ gsum, int N)
{
    const int lane = threadIdx.x & 63;
    const int wid  = blockIdx.x * (blockDim.x >> 6) + (threadIdx.x >> 6);
    const int nw   = gridDim.x * (blockDim.x >> 6);
    for (int n = wid; n < N; n += nw) {
        const int nu = __builtin_amdgcn_readfirstlane(n);
        const int b = batch[nu];
        unsafeAtomicAdd(&gsum[(size_t)b * DIM + lane], h[(size_t)nu * DIM + lane]);
    }
}

// ---------------- head: g=relu(mean@postW+postb); out = g@outW+outb ----------------
__global__ __launch_bounds__(64) void head(const float* __restrict__ gsum,
                                           const float* __restrict__ cnt,
                                           const float* __restrict__ postW,
                                           const float* __restrict__ postb,
                                           const float* __restrict__ outW,
                                           const float* __restrict__ outb,
                                           float* __restrict__ out)
{
    const int gi = blockIdx.x;
    const int lane = threadIdx.x;
    const float inv = 1.f / fmaxf(cnt[gi], 1.f);
    const float gval = gsum[(size_t)gi * DIM + lane] * inv;
    float acc = postb[lane];
#pragma unroll
    for (int k = 0; k < DIM; ++k) acc = fmaf(__shfl(gval, k, 64), postW[k * DIM + lane], acc);
    const float t = fmaxf(acc, 0.f);
    float prod = t * outW[lane];
#pragma unroll
    for (int off = 32; off > 0; off >>= 1) prod += __shfl_down(prod, off, 64);
    if (lane == 0) out[gi] = prod + outb[0];
}

extern "C" void kernel_launch(void* const* d_in, const int* in_sizes, int n_in,
                              void* d_out, int out_size, void* d_ws, size_t ws_size,
                              hipStream_t stream)
{
    const float* x     = (const float*)d_in[0];
    const int*   ei    = (const int*)d_in[1];
    const float* eattr = (const float*)d_in[2];
    const int*   batch = (const int*)d_in[3];
    const float* preW  = (const float*)d_in[4];
    const float* preb  = (const float*)d_in[5];
    const float* Wf    = (const float*)d_in[6];
    const float* bf    = (const float*)d_in[7];
    const float* Ws    = (const float*)d_in[8];
    const float* bs    = (const float*)d_in[9];
    const float* gamma = (const float*)d_in[10];
    const float* beta  = (const float*)d_in[11];
    const float* mean  = (const float*)d_in[12];
    const float* var   = (const float*)d_in[13];
    const float* postW = (const float*)d_in[14];
    const float* postb = (const float*)d_in[15];
    const float* outW  = (const float*)d_in[16];
    const float* outb  = (const float*)d_in[17];
    float* out = (float*)d_out;

    const int N = N_NODES, E = N_EDGES, G = NGRAPH;

    char* p = (char*)d_ws;
    float* h      = (float*)p; p += (size_t)N * DIM * 4;
    float* Pd     = (float*)p; p += (size_t)N * 128 * 4;
    float* Ps     = (float*)p; p += (size_t)N * 128 * 4;
    float* agg    = (float*)p; p += (size_t)N * DIM * 4;
    // zeroed-together block: gsum | cnt | deg
    float* gsum   = (float*)p; p += (size_t)G * DIM * 4;
    float* cnt    = (float*)p; p += (size_t)G * 4;
    float* deg    = (float*)p; p += (size_t)N * 4;
    unsigned short* Wnh = (unsigned short*)p; p += (size_t)NLAYER * 256 * 64 * 2;
    unsigned short* Wnl = (unsigned short*)p; p += (size_t)NLAYER * 256 * 64 * 2;
    float* pbias  = (float*)p; p += (size_t)NLAYER * 256 * 4;

    hipMemsetAsync(gsum, 0, ((size_t)G * DIM + G + N) * 4, stream);

    deg_cnt<<<512, 256, 0, stream>>>(ei, E, batch, N, deg, cnt);
    prep_nwsplit<<<(NLAYER * 256 * 64 + 255) / 256, 256, 0, stream>>>(Wf, Ws, bf, bs,
                                                                      Wnh, Wnl, pbias);

    pre_fc<<<512, 256, 0, stream>>>(x, preW, preb, h, N);

    const int nblk = (N + 63) / 64;
    for (int l = 0; l < NLAYER; ++l) {
        const float* Wfl = Wf + (size_t)l * ZROWS * DIM;
        const float* Wsl = Ws + (size_t)l * ZROWS * DIM;
        hipMemsetAsync(agg, 0, (size_t)N * DIM * 4, stream);
        node_proj_mfma<<<nblk, 512, 0, stream>>>(h,
                                                 Wnh + (size_t)l * 16384,
                                                 Wnl + (size_t)l * 16384,
                                                 pbias + (size_t)l * 256, Pd, Ps, N);
        edge_fused<<<E / 64, 512, 0, stream>>>(ei, eattr, Pd, Ps,
                                               Wfl + 2 * DIM * DIM, Wsl + 2 * DIM * DIM,
                                               agg, E);
        node_update<<<1024, 256, 0, stream>>>(h, agg, deg, gamma + l * DIM, beta + l * DIM,
                                              mean + l * DIM, var + l * DIM, N);
    }

    pool_sum<<<512, 256, 0, stream>>>(h, batch, gsum, N);
    head<<<G, 64, 0, stream>>>(gsum, cnt, postW, postb, outW, outb, out);
}

// Round 16
// 1078.251 us; speedup vs baseline: 1.3264x; 1.0158x over previous
//
#include <hip/hip_runtime.h>
#include <cmath>

#define N_NODES 50000
#define N_EDGES 800000
#define F_IN 92
#define DIM 64
#define EF 50
#define NLAYER 3
#define NGRAPH 128
#define ZROWS 178   // 2*DIM + EF

// ---------------- pre FC: h = relu(x @ pre_W + pre_b) ----------------
__global__ __launch_bounds__(256, 3) void pre_fc(const float* __restrict__ x,
                                                 const float* __restrict__ W,
                                                 const float* __restrict__ b,
                                                 float* __restrict__ h, int N)
{
    const int lane = threadIdx.x & 63;
    const int wid  = blockIdx.x * (blockDim.x >> 6) + (threadIdx.x >> 6);
    const int nw   = gridDim.x * (blockDim.x >> 6);
    float w[F_IN];
#pragma unroll
    for (int k = 0; k < F_IN; ++k) w[k] = W[k * DIM + lane];
    const float bb = b[lane];
#pragma unroll 1
    for (int n = wid; n < N; n += nw) {
        const int nu = __builtin_amdgcn_readfirstlane(n);
        const float* xr = x + (size_t)nu * F_IN;
        float a = bb;
#pragma unroll
        for (int k = 0; k < F_IN; ++k) a = fmaf(xr[k], w[k], a);
        h[(size_t)nu * DIM + lane] = fmaxf(a, 0.f);
    }
}

// ---------------- degree + graph-node counts ----------------
__global__ __launch_bounds__(256) void deg_cnt(const int* __restrict__ ei, int E,
                                               const int* __restrict__ batch, int N,
                                               float* __restrict__ deg,
                                               float* __restrict__ cnt)
{
    const int i = blockIdx.x * blockDim.x + threadIdx.x;
    const int stride = gridDim.x * blockDim.x;
    for (int e = i; e < E; e += stride) unsafeAtomicAdd(&deg[ei[E + e]], 1.f);
    for (int n = i; n < N; n += stride) unsafeAtomicAdd(&cnt[batch[n]], 1.f);
}

// ---------------- node projections for layer l (scalar, r7 config) ----------
// Pd[n] = [ h@Wf[0:64] + bf | h@Ws[0:64] + bs ]   (dst/i, biases folded)
// Ps[n] = [ h@Wf[64:128]    | h@Ws[64:128]     ]  (src/j)
__global__ __launch_bounds__(256, 2) void node_proj(const float* __restrict__ h,
                                                    const float* __restrict__ Wfl,
                                                    const float* __restrict__ Wsl,
                                                    const float* __restrict__ bf,
                                                    const float* __restrict__ bs,
                                                    float* __restrict__ Pd,
                                                    float* __restrict__ Ps, int N)
{
    const int lane = threadIdx.x & 63;
    const int wid  = blockIdx.x * (blockDim.x >> 6) + (threadIdx.x >> 6);
    const int nw   = gridDim.x * (blockDim.x >> 6);
    const int half = wid & 1;  // 0 -> Pd, 1 -> Ps
    const float* wfb = Wfl + (half ? DIM * DIM : 0);
    const float* wsb = Wsl + (half ? DIM * DIM : 0);
    float wf[DIM], ws[DIM];
#pragma unroll
    for (int k = 0; k < DIM; ++k) { wf[k] = wfb[k * DIM + lane]; ws[k] = wsb[k * DIM + lane]; }
    const float b0 = half ? 0.f : bf[lane];
    const float b1 = half ? 0.f : bs[lane];
    float* P = half ? Ps : Pd;
#pragma unroll 1
    for (int n = (wid >> 1); n < N; n += (nw >> 1)) {
        const int nu = __builtin_amdgcn_readfirstlane(n);
        const float* hr = h + (size_t)nu * DIM;
        float a0 = b0, a1 = b1;
#pragma unroll
        for (int k = 0; k < DIM; ++k) {
            const float v = hr[k];
            a0 = fmaf(v, wf[k], a0);
            a1 = fmaf(v, ws[k], a1);
        }
        P[(size_t)nu * 128 + lane]      = a0;
        P[(size_t)nu * 128 + 64 + lane] = a1;
    }
}

// ---------------- fused edge kernel (r7 structure, batched phase B) ----------
// One block = 512 threads (8 waves) = one tile of 64 edges.
// Phase A: wave wv computes 16 cols of the 128-dim eattr projection for all
//   64 edges; weight operand wave-uniform -> s_load (zero VGPR pressure).
// Phase B: wave wv handles 8 edges, lane = dim; ALL 32 row-gathers issued
//   branchlessly before any gate math (one latency round-trip, not 8).
#define EA_PAD 51   // odd stride -> conflict-free by-row and by-col access
#define TP_PAD 129  // odd stride -> conflict-free write (lane=e) and read (lane=dim)
__global__ __launch_bounds__(512) void edge_fused(const int* __restrict__ ei,
                                                  const float* __restrict__ eattr,
                                                  const float* __restrict__ Pd,
                                                  const float* __restrict__ Ps,
                                                  const float* __restrict__ WfE,
                                                  const float* __restrict__ WsE,
                                                  float* __restrict__ agg, int E)
{
    __shared__ float ea_lds[64 * EA_PAD];
    __shared__ float out_lds[64 * TP_PAD];

    const int tid = threadIdx.x;
    const int e0  = blockIdx.x * 64;

    // ---- stage 64 eattr rows (coalesced global read) ----
    {
        const float* src = eattr + (size_t)e0 * EF;
        for (int idx = tid; idx < 64 * EF; idx += 512) {
            const int e = idx / EF;
            const int k = idx - e * EF;
            ea_lds[e * EA_PAD + k] = src[idx];
        }
    }
    __syncthreads();

    // ---- phase A: projection, lane = edge, 16 cols per wave ----
    {
        const int e  = tid & 63;
        const int wv = __builtin_amdgcn_readfirstlane(tid >> 6);  // 0..7, uniform
        const float* Wbase = (wv < 4) ? WfE : WsE;   // uniform pointer
        const int c0 = (wv & 3) * 16;                // uniform col offset in [0,64)
        const int cb = ((wv < 4) ? 0 : 64) + c0;     // output col base in [0,128)

        float acc[16];
#pragma unroll
        for (int j = 0; j < 16; ++j) acc[j] = 0.f;

        const float* ear = ea_lds + e * EA_PAD;
#pragma unroll 5
        for (int k = 0; k < EF; ++k) {
            const float eak = ear[k];                 // ds_read, conflict-free
            const float* wr = Wbase + k * DIM + c0;   // uniform -> s_load
#pragma unroll
            for (int j = 0; j < 16; ++j) acc[j] = fmaf(eak, wr[j], acc[j]);
        }
        float* orow = out_lds + e * TP_PAD + cb;
#pragma unroll
        for (int j = 0; j < 16; ++j) orow[j] = acc[j];
    }
    __syncthreads();

    // ---- phase B: batched gathers, then gate + scatter, lane = dim ----
    {
        const int lane = tid & 63;
        const int wv   = __builtin_amdgcn_readfirstlane(tid >> 6);
        const int base = e0 + wv * 8;

        int dd[8], ss[8];
#pragma unroll
        for (int i = 0; i < 8; ++i) {
            dd[i] = ei[E + base + i];     // uniform -> s_load
            ss[i] = ei[base + i];
        }
        float pd0[8], pd1[8], ps0[8], ps1[8];
#pragma unroll
        for (int i = 0; i < 8; ++i) {     // 32 independent gathers in flight
            const float* pdr = Pd + (size_t)dd[i] * 128;
            const float* psr = Ps + (size_t)ss[i] * 128;
            pd0[i] = pdr[lane]; pd1[i] = pdr[64 + lane];
            ps0[i] = psr[lane]; ps1[i] = psr[64 + lane];
        }
#pragma unroll
        for (int i = 0; i < 8; ++i) {
            const int el = wv * 8 + i;
            const float zf = out_lds[el * TP_PAD + lane]      + pd0[i] + ps0[i];
            const float zs = out_lds[el * TP_PAD + 64 + lane] + pd1[i] + ps1[i];
            const float sig = 1.f / (1.f + __expf(-zf));
            const float sp  = fmaxf(zs, 0.f) + __logf(1.f + __expf(-fabsf(zs)));
            unsafeAtomicAdd(&agg[(size_t)dd[i] * DIM + lane], sig * sp);
        }
    }
}

// ---------------- node update: h = BN(h + agg/deg) ----------------
__global__ __launch_bounds__(256) void node_update(float* __restrict__ h,
                                                   const float* __restrict__ agg,
                                                   const float* __restrict__ deg,
                                                   const float* __restrict__ gamma,
                                                   const float* __restrict__ beta,
                                                   const float* __restrict__ mean,
                                                   const float* __restrict__ var, int N)
{
    const int lane = threadIdx.x & 63;
    const float g  = gamma[lane];
    const float bt = beta[lane];
    const float mn = mean[lane];
    const float iv = rsqrtf(var[lane] + 1e-5f);
    const int idx = blockIdx.x * blockDim.x + threadIdx.x;
    const int stride = gridDim.x * blockDim.x;  // multiple of 64
    const int total = N * DIM;
    for (int i = idx; i < total; i += stride) {
        const int n = i >> 6;
        const float inv = 1.f / fmaxf(deg[n], 1.f);
        const float v = h[i] + agg[i] * inv;
        h[i] = fmaf(g, (v - mn) * iv, bt);
    }
}

// ---------------- global mean pool (sum part) ----------------
__global__ __launch_bounds__(256) void pool_sum(const float* __restrict__ h,
                                                const int* __restrict__ batch,
                                                float* __restrict__ gsum, int N)
{
    const int lane = threadIdx.x & 63;
    const int wid  = blockIdx.x * (blockDim.x >> 6) + (threadIdx.x >> 6);
    const int nw   = gridDim.x * (blockDim.x >> 6);
    for (int n = wid; n < N; n += nw) {
        const int nu = __builtin_amdgcn_readfirstlane(n);
        const int b = batch[nu];
        unsafeAtomicAdd(&gsum[(size_t)b * DIM + lane], h[(size_t)nu * DIM + lane]);
    }
}

// ---------------- head: g=relu(mean@postW+postb); out = g@outW+outb ----------------
__global__ __launch_bounds__(64) void head(const float* __restrict__ gsum,
                                           const float* __restrict__ cnt,
                                           const float* __restrict__ postW,
                                           const float* __restrict__ postb,
                                           const float* __restrict__ outW,
                                           const float* __restrict__ outb,
                                           float* __restrict__ out)
{
    const int gi = blockIdx.x;
    const int lane = threadIdx.x;
    const float inv = 1.f / fmaxf(cnt[gi], 1.f);
    const float gval = gsum[(size_t)gi * DIM + lane] * inv;
    float acc = postb[lane];
#pragma unroll
    for (int k = 0; k < DIM; ++k) acc = fmaf(__shfl(gval, k, 64), postW[k * DIM + lane], acc);
    const float t = fmaxf(acc, 0.f);
    float prod = t * outW[lane];
#pragma unroll
    for (int off = 32; off > 0; off >>= 1) prod += __shfl_down(prod, off, 64);
    if (lane == 0) out[gi] = prod + outb[0];
}

extern "C" void kernel_launch(void* const* d_in, const int* in_sizes, int n_in,
                              void* d_out, int out_size, void* d_ws, size_t ws_size,
                              hipStream_t stream)
{
    const float* x     = (const float*)d_in[0];
    const int*   ei    = (const int*)d_in[1];
    const float* eattr = (const float*)d_in[2];
    const int*   batch = (const int*)d_in[3];
    const float* preW  = (const float*)d_in[4];
    const float* preb  = (const float*)d_in[5];
    const float* Wf    = (const float*)d_in[6];
    const float* bf    = (const float*)d_in[7];
    const float* Ws    = (const float*)d_in[8];
    const float* bs    = (const float*)d_in[9];
    const float* gamma = (const float*)d_in[10];
    const float* beta  = (const float*)d_in[11];
    const float* mean  = (const float*)d_in[12];
    const float* var   = (const float*)d_in[13];
    const float* postW = (const float*)d_in[14];
    const float* postb = (const float*)d_in[15];
    const float* outW  = (const float*)d_in[16];
    const float* outb  = (const float*)d_in[17];
    float* out = (float*)d_out;

    const int N = N_NODES, E = N_EDGES, G = NGRAPH;

    char* p = (char*)d_ws;
    float* h      = (float*)p; p += (size_t)N * DIM * 4;
    float* Pd     = (float*)p; p += (size_t)N * 128 * 4;
    float* Ps     = (float*)p; p += (size_t)N * 128 * 4;
    float* agg    = (float*)p; p += (size_t)N * DIM * 4;
    // zeroed-together block: gsum | cnt | deg
    float* gsum   = (float*)p; p += (size_t)G * DIM * 4;
    float* cnt    = (float*)p; p += (size_t)G * 4;
    float* deg    = (float*)p; p += (size_t)N * 4;

    hipMemsetAsync(gsum, 0, ((size_t)G * DIM + G + N) * 4, stream);

    deg_cnt<<<512, 256, 0, stream>>>(ei, E, batch, N, deg, cnt);
    pre_fc<<<512, 256, 0, stream>>>(x, preW, preb, h, N);

    for (int l = 0; l < NLAYER; ++l) {
        const float* Wfl = Wf + (size_t)l * ZROWS * DIM;
        const float* Wsl = Ws + (size_t)l * ZROWS * DIM;
        hipMemsetAsync(agg, 0, (size_t)N * DIM * 4, stream);
        node_proj<<<512, 256, 0, stream>>>(h, Wfl, Wsl, bf + l * DIM, bs + l * DIM, Pd, Ps, N);
        edge_fused<<<E / 64, 512, 0, stream>>>(ei, eattr, Pd, Ps,
                                               Wfl + 2 * DIM * DIM, Wsl + 2 * DIM * DIM,
                                               agg, E);
        node_update<<<1024, 256, 0, stream>>>(h, agg, deg, gamma + l * DIM, beta + l * DIM,
                                              mean + l * DIM, var + l * DIM, N);
    }

    pool_sum<<<512, 256, 0, stream>>>(h, batch, gsum, N);
    head<<<G, 64, 0, stream>>>(gsum, cnt, postW, postb, outW, outb, out);
}